// Round 12
// baseline (96647.382 us; speedup 1.0000x reference)
//
#include <hip/hip_runtime.h>
#include <cstdint>
#include <cstddef>

// LowRankRNN: h_{t+1} = h + coef*(-h + J@relu(h) + I_t),  J = G*W - B/N + M u v^T
//
// R12: SINGLE-XCD EXCHANGE. R4..R11 established that the step time (~4850cy)
// is pinned by the cross-XCD publish->poll round trip at the die-level
// coherence point (sc1/LLC, ~600-900cy; FETCH shows ~22KB/step of x-line
// refetch). The fix is topological: the 64 worker blocks (32 CUs' worth at
// 2 blocks/CU) fit in ONE XCD, whose private L2 (4MB, shared by its 32 CUs)
// can be the coherence point at ~200-300cy RT.
//
//  - Launch 512 blocks = exact device capacity at 2 blocks/CU (VGPR<=128,
//    LDS 16KB) => all co-resident => each XCD hosts exactly 64.
//  - Each block reads HW_REG_XCC_ID; XCD0 blocks claim worker slots 0..63
//    from an atomic counter; all others exit once the count fills.
//    DEADLOCK-PROOF fallback: if the count hasn't filled after a one-time
//    timeout (placement not round-robin), any block may claim — 64 workers
//    always materialize; misplaced workers only lose the fast path.
//  - Dual publish: lane0 stores the sign-encoded x-chunk to xfast (sc0:
//    write-through to local L2) AND xslow (sc1: device scope, the proven
//    R8/R11 path). Consumers poll xfast with sc0 loads (L1-bypass, L2-hit).
//    A wave whose fast poll fails >64 rounds escalates PERMANENTLY to the
//    sc1/xslow path. The sign-phase protocol makes stale fast data inert
//    (wrong phase never passes), so correctness is placement-independent.
//  - Loop body, FMA order, reduce, encodings: bit-identical to R11
//    (lgkm-only barrier kept).
//
// Overwrite safety unchanged: publishing x(t+2) requires having acquired all
// of x(t+1) => every block's step-t barrier passed => all step-t reads of
// buffer t&1 done. Per-dword store atomicity + per-word sign check handle
// partial arrival. Both xfast and xslow obey the same phase discipline.

constexpr int   NN   = 2048;
constexpr int   TT   = 8192;
constexpr float COEF = 0.001f;             // DT/TAU
constexpr float G_   = 2.0f;
constexpr float BOFF = 10.0f / 2048.0f;    // B/N
constexpr float M_   = 1.5f;

constexpr int NWORK = 64;   // worker blocks (on one XCD)
constexpr int NBLK  = 512;  // launched blocks = device capacity at 2/CU
constexpr int TPB   = 512;  // 8 waves
constexpr int WPB   = TPB / 64;

typedef float f32x4 __attribute__((ext_vector_type(4)));
typedef int   i32x4 __attribute__((ext_vector_type(4)));

__device__ __forceinline__ i32x4 bc(const f32x4 x) { return __builtin_bit_cast(i32x4, x); }
__device__ __forceinline__ f32x4 fc(const i32x4 x) { return __builtin_bit_cast(f32x4, x); }

// phase0 polled first at t=2 expecting sign-SET  -> init sign-clear (waits)
// phase1 polled first at t=1 expecting sign-CLEAR -> init sign-set  (waits)
__global__ void init_ws(float* xf, float* xs, unsigned* ctr) {
  const int i = blockIdx.x * blockDim.x + threadIdx.x;   // 0..NN-1
  if (i == 0) *ctr = 0u;
  xf[i] = 0.0f;  xf[NN + i] = -1.0f;
  xs[i] = 0.0f;  xs[NN + i] = -1.0f;
}

// FAST path: sc0 (L1-bypass; local-L2 coherence point). 16B + waitcnt in one
// asm block (consumers ordered by register dataflow; rule-#18 safe).
__device__ __forceinline__ f32x4 poll_fast(const float* p) {
  f32x4 c;
  asm volatile("global_load_dwordx4 %0, %1, off sc0\n\t"
               "s_waitcnt vmcnt(0)"
               : "=&v"(c) : "v"(p) : "memory");
  return c;
}
__device__ __forceinline__ void store_fast(float* p, f32x4 v) {
  asm volatile("global_store_dwordx4 %0, %1, off sc0"
               :: "v"(p), "v"(v) : "memory");
}
// SLOW/SURE path: sc1 device scope (the measured-correct R8/R11 exchange).
__device__ __forceinline__ f32x4 poll_slow(const float* p) {
  f32x4 c;
  asm volatile("global_load_dwordx4 %0, %1, off sc1\n\t"
               "s_waitcnt vmcnt(0)"
               : "=&v"(c) : "v"(p) : "memory");
  return c;
}
__device__ __forceinline__ void store_slow(float* p, f32x4 v) {
  asm volatile("global_store_dwordx4 %0, %1, off sc1"
               :: "v"(p), "v"(v) : "memory");
}

// LDS-only barrier (R11): lgkmcnt(0)+s_barrier, no vmcnt drain.
__device__ __forceinline__ void lds_barrier() {
  asm volatile("s_waitcnt lgkmcnt(0)\n\t"
               "s_barrier" ::: "memory");
}

__device__ __forceinline__ bool chk(const f32x4 v, const bool enc) {
  const i32x4 b = bc(v);
  if (enc) return __all(((b.x & b.y) & (b.z & b.w)) < 0) != 0;
  else     return __all(((b.x | b.y) | (b.z | b.w)) >= 0) != 0;
}

// butterfly helpers — value-identical to p += __shfl_xor(p, m)
template <int CTRL>
__device__ __forceinline__ float xadd_dpp(float v) {
  const int t = __builtin_amdgcn_update_dpp(0, __builtin_bit_cast(int, v),
                                            CTRL, 0xF, 0xF, false);
  return v + __builtin_bit_cast(float, t);
}
template <int PAT>
__device__ __forceinline__ float xadd_swz(float v) {
  const int t = __builtin_amdgcn_ds_swizzle(__builtin_bit_cast(int, v), PAT);
  return v + __builtin_bit_cast(float, t);
}

__global__ __launch_bounds__(TPB, 4)   // 4 waves/SIMD = 2 blocks/CU co-residency
void rnn_persist(const float* __restrict__ I_t,
                 const float* __restrict__ h0,
                 const float* __restrict__ W,
                 const float* __restrict__ u,
                 const float* __restrict__ v,
                 float* __restrict__ out_h,   // d_out + TT, [TT][NN]
                 float* __restrict__ xfast,   // 2*NN floats (sc0 domain)
                 float* __restrict__ xslow,   // 2*NN floats (sc1 domain)
                 unsigned* __restrict__ ctr)  // worker-slot counter
{
  __shared__ f32x4 xs[2][NN / 4];             // 16 KB, double-buffered x
  __shared__ int sh_bid;

  const int tid = threadIdx.x;

  // ---- worker-slot claim: XCD0 blocks claim immediately; others wait for
  // fill or (one-time) timeout then fallback-claim. 64 workers guaranteed.
  if (tid == 0) {
    unsigned xcc = 0;
    asm volatile("s_getreg_b32 %0, hwreg(HW_REG_XCC_ID)" : "=s"(xcc));
    int bid = -1;
    if (xcc == 0) {
      const unsigned s = __hip_atomic_fetch_add(ctr, 1u, __ATOMIC_RELAXED,
                                                __HIP_MEMORY_SCOPE_AGENT);
      if (s < (unsigned)NWORK) bid = (int)s;
    }
    if (bid < 0) {
      const unsigned long long t0 = __builtin_amdgcn_s_memrealtime();
      for (;;) {
        const unsigned c = __hip_atomic_load(ctr, __ATOMIC_RELAXED,
                                             __HIP_MEMORY_SCOPE_AGENT);
        if (c >= (unsigned)NWORK) break;
        if (__builtin_amdgcn_s_memrealtime() - t0 > 200000ull) {  // ~2ms
          const unsigned s = __hip_atomic_fetch_add(ctr, 1u, __ATOMIC_RELAXED,
                                                    __HIP_MEMORY_SCOPE_AGENT);
          if (s < (unsigned)NWORK) bid = (int)s;
          break;
        }
      }
    }
    sh_bid = bid;
  }
  __syncthreads();
  const int bid = sh_bid;
  if (bid < 0) return;                          // non-worker: free the CU

  const int l   = tid & 63;
  const int w   = tid >> 6;
  const int gw  = bid * WPB + w;                // global wave 0..511
  const int rb  = gw * 4;                       // this wave's 4 rows
  const int cb  = l * 4;                        // column base per 256-chunk

  // ---- J rows rb..rb+3: J[j][k] <-> row rb+j, cols k*256 + 4l
  f32x4 J[4][8];
#pragma unroll
  for (int j = 0; j < 4; ++j) {
    const float mu = M_ * u[rb + j];
#pragma unroll
    for (int k = 0; k < 8; ++k) {
      const int c = k * 256 + cb;
      const f32x4 wv = *(const f32x4*)(W + (size_t)(rb + j) * NN + c);
      const f32x4 vv = *(const f32x4*)(v + c);
      J[j][k] = G_ * wv - BOFF + mu * vv;
    }
  }

  float h[4];
#pragma unroll
  for (int j = 0; j < 4; ++j) h[j] = h0[rb + j];

  const f32x4 zero4 = {0.f, 0.f, 0.f, 0.f};

  // I_t pipeline: parity-selected regs, issued ~1 step ahead of use
  f32x4 iva = *(const f32x4*)(I_t + rb);              // row 0
  f32x4 ivb = *(const f32x4*)(I_t + (size_t)NN + rb); // row 1 (in flight)

  bool fastok = true;   // sticky per-wave: fast path until proven stale

  for (int t = 0; t < TT; ++t) {
    const f32x4 icur4 = (t & 1) ? ivb : iva;
    const int bsel = t & 1;

    // ---- acquire this wave's chunk w of x(t)
    f32x4 c;
    if (t == 0) {
      const f32x4 hv = *(const f32x4*)(h0 + w * 256 + cb);
      c = __builtin_elementwise_max(hv, zero4);   // x(0) = relu(h0)
    } else {
      const bool enc = ((t >> 1) & 1) != 0;       // x(t) stored sign-flipped?
      const int off = bsel * NN + w * 256 + cb;
      unsigned spins = 0;
      if (fastok) {
        for (;;) {  // fast: sc0 poll of local-L2 buffer (~250cy rounds)
          c = poll_fast(xfast + off);
          if (chk(c, enc)) break;
          if (++spins > 64u) { fastok = false; break; }   // escalate, sticky
        }
      }
      if (!fastok) {
        for (;;) {  // sure: sc1 poll of device-scope buffer (R8/R11 path)
          c = poll_slow(xslow + off);
          if (chk(c, enc)) break;
          if (++spins > (1u << 22)) break;        // escape hatch; never hit
        }
      }
      i32x4 b = bc(c);
      b &= 0x7fffffff;                            // exact decode: clear sign
      c = __builtin_bit_cast(f32x4, b);
    }

    // ---- issue I_t row t+2 now (retires lazily; lgkm-only barrier)
    if (t + 2 < TT) {
      const f32x4 nv = *(const f32x4*)(I_t + (size_t)(t + 2) * NN + rb);
      if (t & 1) ivb = nv; else iva = nv;
    }

    xs[bsel][w * 64 + l] = c;                     // ds_write_b128
    lds_barrier();   // lgkmcnt(0) + s_barrier — no vmcnt drain

    // ---- p = J @ x from LDS (values already relu'd + decoded)
    f32x4 p4[4] = {zero4, zero4, zero4, zero4};
#pragma unroll
    for (int k = 0; k < 8; ++k) {
      const f32x4 xv = xs[bsel][k * 64 + l];      // ds_read_b128, conflict-free
#pragma unroll
      for (int j = 0; j < 4; ++j)
        p4[j] = __builtin_elementwise_fma(J[j][k], xv, p4[j]);  // v_pk_fma_f32
    }
    float p[4];
#pragma unroll
    for (int j = 0; j < 4; ++j)
      p[j] = (p4[j].x + p4[j].y) + (p4[j].z + p4[j].w);

    // ---- wave allreduce, same pairing order as p += __shfl_xor(p, m) for
    // m = 32,16,8,4,2,1 (bit-identical), DPP/swizzle for low latency.
#pragma unroll
    for (int j = 0; j < 4; ++j) {
      p[j] += __shfl_xor(p[j], 32, 64);     // xor32 (ds_permute/permlane)
      p[j] = xadd_swz<0x401F>(p[j]);        // xor16 (ds_swizzle)
      p[j] = xadd_dpp<0x128>(p[j]);         // xor8  (DPP row_ror:8)
      p[j] = xadd_swz<0x101F>(p[j]);        // xor4  (ds_swizzle)
      p[j] = xadd_dpp<0x4E>(p[j]);          // xor2  (DPP quad_perm [2,3,0,1])
      p[j] = xadd_dpp<0xB1>(p[j]);          // xor1  (DPP quad_perm [1,0,3,2])
    }

    const float ic[4] = {icur4.x, icur4.y, icur4.z, icur4.w};
#pragma unroll
    for (int j = 0; j < 4; ++j)
      h[j] = fmaf(COEF, p[j] + ic[j] - h[j], h[j]);

    // ---- publish x(t+1) = relu(h), sign-encoded, DUAL: fast (sc0, local
    // L2) + sure (sc1, device). This IS the barrier.
    if (t + 1 < TT) {
      const bool encN = (((t + 1) >> 1) & 1) != 0;
      if (l == 0) {
        i32x4 e;
        e.x = __builtin_bit_cast(int, fmaxf(h[0], 0.f));
        e.y = __builtin_bit_cast(int, fmaxf(h[1], 0.f));
        e.z = __builtin_bit_cast(int, fmaxf(h[2], 0.f));
        e.w = __builtin_bit_cast(int, fmaxf(h[3], 0.f));
        if (encN) e |= 0x80000000; else e &= 0x7fffffff;
        const int doff = ((t + 1) & 1) * NN + rb;
        store_fast(xfast + doff, fc(e));
        store_slow(xslow + doff, fc(e));
      }
    }
    // trace store: plain cached store (ack retires under the next poll)
    if (l == 0) {
      f32x4 hv; hv.x = h[0]; hv.y = h[1]; hv.z = h[2]; hv.w = h[3];
      *(f32x4*)(out_h + (size_t)t * NN + rb) = hv;
    }
  }
}

__global__ __launch_bounds__(256)
void readout(const float* __restrict__ h_all,
             const float* __restrict__ ro_w,
             const float* __restrict__ ro_b,
             float* __restrict__ y)
{
  __shared__ float red[4];
  const int t   = blockIdx.x;
  const int tid = threadIdx.x;
  const float* h = h_all + (size_t)t * NN;
  const int base = tid * 8;

  const float4 a0 = *(const float4*)(h + base);
  const float4 a1 = *(const float4*)(h + base + 4);
  const float4 w0 = *(const float4*)(ro_w + base);
  const float4 w1 = *(const float4*)(ro_w + base + 4);

  float s = a0.x * w0.x + a0.y * w0.y + a0.z * w0.z + a0.w * w0.w
          + a1.x * w1.x + a1.y * w1.y + a1.z * w1.z + a1.w * w1.w;
#pragma unroll
  for (int m = 32; m >= 1; m >>= 1) s += __shfl_xor(s, m, 64);

  if ((tid & 63) == 0) red[tid >> 6] = s;
  __syncthreads();
  if (tid == 0) y[t] = red[0] + red[1] + red[2] + red[3] + ro_b[0];
}

extern "C" void kernel_launch(void* const* d_in, const int* in_sizes, int n_in,
                              void* d_out, int out_size, void* d_ws, size_t ws_size,
                              hipStream_t stream)
{
  const float* I_t  = (const float*)d_in[0];
  const float* h0   = (const float*)d_in[1];
  const float* W    = (const float*)d_in[2];
  const float* u    = (const float*)d_in[3];
  const float* v    = (const float*)d_in[4];
  const float* ro_w = (const float*)d_in[5];
  const float* ro_b = (const float*)d_in[6];

  float* y    = (float*)d_out;             // [TT]
  float* outh = (float*)d_out + TT;        // [TT][NN]

  unsigned* ctr = (unsigned*)d_ws;                         // 1 counter
  float* xfast  = (float*)((char*)d_ws + 256);             // 2*NN floats
  float* xslow  = xfast + 2 * NN;                          // 2*NN floats

  init_ws<<<NN / TPB, TPB, 0, stream>>>(xfast, xslow, ctr);
  rnn_persist<<<NBLK, TPB, 0, stream>>>(I_t, h0, W, u, v, outh, xfast, xslow, ctr);
  readout<<<TT, 256, 0, stream>>>(outh, ro_w, ro_b, y);
}

// Round 13
// 16706.441 us; speedup vs baseline: 5.7850x; 5.7850x over previous
//
#include <hip/hip_runtime.h>
#include <cstdint>
#include <cstddef>

// LowRankRNN: h_{t+1} = h + coef*(-h + J@relu(h) + I_t),  J = G*W - B/N + M u v^T
//
// Persistent kernel, 64 blocks x 512 threads (1 block/CU), J in registers.
// Sync: sign-bit-encoded data IS the flag (x = relu(h) >= 0; x(t) stored with
// sign bit forced to phase enc(t)=(t>>1)&1; decode = clear sign bit; two
// buffers alternate by t&1 so stale data never satisfies a poll).
// Wave w polls only its chunk w (1 dwordx4/lane), decodes into LDS, barrier,
// all waves read x from LDS.
//
// R13 = R11 VERBATIM RESTORE (measured best: 16.55ms).
//   R12's single-XCD placement experiment regressed 6x (FETCH 26.9GB: the
//   claim/exit machinery broke the exchange; placement control is unsafe
//   from HIP on this harness). Experiment matrix R4..R12: replication,
//   LDS-spin (x2), scope bits, drain placement (x3), counted-vmcnt
//   pipelining (hang), XCD placement (catastrophe) — ALL null or negative
//   against the R4/R11 structure. The step time (~4850cy) is pinned by the
//   device-wide publish->detect round trip via the memory-side LLC plus
//   slowest-of-64 straggler statistics; no instruction-level lever moved it.
//
// R11's one improvement over R4/R8 (kept): LGKM-ONLY BARRIER —
//   "s_waitcnt lgkmcnt(0); s_barrier" instead of __syncthreads' vmcnt(0)
//   drain; the I_t prefetch / store-acks retire lazily under the next poll.
//
// Overwrite safety: publishing x(t+2) requires having acquired all of
// x(t+1), which required every block's step-t barrier, i.e. all step-t
// reads of buffer t&1 are done before anyone can write it again. Per-dword
// store atomicity + per-word sign check handle partial arrival.

constexpr int   NN   = 2048;
constexpr int   TT   = 8192;
constexpr float COEF = 0.001f;             // DT/TAU
constexpr float G_   = 2.0f;
constexpr float BOFF = 10.0f / 2048.0f;    // B/N
constexpr float M_   = 1.5f;

constexpr int NBLK = 64;    // 1 block/CU
constexpr int TPB  = 512;   // 8 waves
constexpr int WPB  = TPB / 64;

typedef float f32x4 __attribute__((ext_vector_type(4)));
typedef int   i32x4 __attribute__((ext_vector_type(4)));

__device__ __forceinline__ i32x4 bc(const f32x4 x) { return __builtin_bit_cast(i32x4, x); }
__device__ __forceinline__ f32x4 fc(const i32x4 x) { return __builtin_bit_cast(f32x4, x); }

// buf0 polled first at t=2 expecting sign-SET  -> init sign-clear (waits)
// buf1 polled first at t=1 expecting sign-CLEAR -> init sign-set  (waits)
__global__ void init_xbufs(float* xb) {
  const int i = blockIdx.x * blockDim.x + threadIdx.x;   // 0..NN-1 over grid
  xb[i]      = 0.0f;
  xb[NN + i] = -1.0f;
}

// One DEVICE-scope 16B load + waitcnt inside one asm block (consumers are
// ordered by register dataflow; rule-#18 safe).
__device__ __forceinline__ f32x4 poll1(const float* p) {
  f32x4 c;
  asm volatile("global_load_dwordx4 %0, %1, off sc1\n\t"
               "s_waitcnt vmcnt(0)"
               : "=&v"(c) : "v"(p) : "memory");
  return c;
}

// DEVICE-scope write-through 16B publish store (visible at the device
// coherence point; per-dword atomicity)
__device__ __forceinline__ void store_wt(float* p, f32x4 v) {
  asm volatile("global_store_dwordx4 %0, %1, off sc1"
               :: "v"(p), "v"(v) : "memory");
}

// LDS-only barrier: orders ds_write (before) / ds_read (after) across the
// block WITHOUT the vmcnt(0) drain __syncthreads would impose. Producer
// write-completion (lgkmcnt(0)) enforced before s_barrier; "memory" clobber
// pins all LDS accesses to the correct side.
__device__ __forceinline__ void lds_barrier() {
  asm volatile("s_waitcnt lgkmcnt(0)\n\t"
               "s_barrier" ::: "memory");
}

// butterfly helpers — value-identical to p += __shfl_xor(p, m)
template <int CTRL>
__device__ __forceinline__ float xadd_dpp(float v) {
  const int t = __builtin_amdgcn_update_dpp(0, __builtin_bit_cast(int, v),
                                            CTRL, 0xF, 0xF, false);
  return v + __builtin_bit_cast(float, t);
}
template <int PAT>
__device__ __forceinline__ float xadd_swz(float v) {
  const int t = __builtin_amdgcn_ds_swizzle(__builtin_bit_cast(int, v), PAT);
  return v + __builtin_bit_cast(float, t);
}

__global__ __launch_bounds__(TPB, 2)
void rnn_persist(const float* __restrict__ I_t,
                 const float* __restrict__ h0,
                 const float* __restrict__ W,
                 const float* __restrict__ u,
                 const float* __restrict__ v,
                 float* __restrict__ out_h,   // d_out + TT, [TT][NN]
                 float* __restrict__ xbuf)    // 2*NN floats
{
  __shared__ f32x4 xs[2][NN / 4];             // 16 KB, double-buffered x

  const int tid = threadIdx.x;
  const int l   = tid & 63;
  const int w   = tid >> 6;
  const int gw  = blockIdx.x * WPB + w;           // global wave 0..511
  const int rb  = gw * 4;                         // this wave's 4 rows
  const int cb  = l * 4;                          // column base per 256-chunk

  // ---- J rows rb..rb+3: J[j][k] <-> row rb+j, cols k*256 + 4l
  f32x4 J[4][8];
#pragma unroll
  for (int j = 0; j < 4; ++j) {
    const float mu = M_ * u[rb + j];
#pragma unroll
    for (int k = 0; k < 8; ++k) {
      const int c = k * 256 + cb;
      const f32x4 wv = *(const f32x4*)(W + (size_t)(rb + j) * NN + c);
      const f32x4 vv = *(const f32x4*)(v + c);
      J[j][k] = G_ * wv - BOFF + mu * vv;
    }
  }

  float h[4];
#pragma unroll
  for (int j = 0; j < 4; ++j) h[j] = h0[rb + j];

  const f32x4 zero4 = {0.f, 0.f, 0.f, 0.f};

  // I_t pipeline: parity-selected regs, issued ~1 step ahead of use
  f32x4 iva = *(const f32x4*)(I_t + rb);              // row 0
  f32x4 ivb = *(const f32x4*)(I_t + (size_t)NN + rb); // row 1 (in flight)

  for (int t = 0; t < TT; ++t) {
    const f32x4 icur4 = (t & 1) ? ivb : iva;
    const int bsel = t & 1;

    // ---- acquire this wave's chunk w of x(t)
    f32x4 c;
    if (t == 0) {
      const f32x4 hv = *(const f32x4*)(h0 + w * 256 + cb);
      c = __builtin_elementwise_max(hv, zero4);   // x(0) = relu(h0)
    } else {
      const bool enc = ((t >> 1) & 1) != 0;       // x(t) stored sign-flipped?
      const float* pb = xbuf + bsel * NN + w * 256 + cb;
      unsigned spins = 0;
      if (enc) {
        for (;;) {  // fresh values have sign SET: all 4 words negative
          c = poll1(pb);
          const i32x4 b = bc(c);
          if (__all(((b.x & b.y) & (b.z & b.w)) < 0)) break;
          if (++spins > (1u << 22)) break;        // escape hatch; never hit
        }
      } else {
        for (;;) {  // fresh values have sign CLEAR: all 4 words non-negative
          c = poll1(pb);
          const i32x4 b = bc(c);
          if (__all(((b.x | b.y) | (b.z | b.w)) >= 0)) break;
          if (++spins > (1u << 22)) break;
        }
      }
      i32x4 b = bc(c);
      b &= 0x7fffffff;                            // exact decode: clear sign
      c = __builtin_bit_cast(f32x4, b);
    }

    // ---- issue I_t row t+2 now. With the lgkm-only barrier it is never
    // force-drained; by the next poll's vmcnt(0) it is ~1 full step old and
    // retires for free.
    if (t + 2 < TT) {
      const f32x4 nv = *(const f32x4*)(I_t + (size_t)(t + 2) * NN + rb);
      if (t & 1) ivb = nv; else iva = nv;
    }

    xs[bsel][w * 64 + l] = c;                     // ds_write_b128
    lds_barrier();   // lgkmcnt(0) + s_barrier — NO vmcnt drain

    // ---- p = J @ x from LDS (values already relu'd + decoded)
    f32x4 p4[4] = {zero4, zero4, zero4, zero4};
#pragma unroll
    for (int k = 0; k < 8; ++k) {
      const f32x4 xv = xs[bsel][k * 64 + l];      // ds_read_b128, conflict-free
#pragma unroll
      for (int j = 0; j < 4; ++j)
        p4[j] = __builtin_elementwise_fma(J[j][k], xv, p4[j]);  // v_pk_fma_f32
    }
    float p[4];
#pragma unroll
    for (int j = 0; j < 4; ++j)
      p[j] = (p4[j].x + p4[j].y) + (p4[j].z + p4[j].w);

    // ---- wave allreduce, same pairing order as p += __shfl_xor(p, m) for
    // m = 32,16,8,4,2,1 (bit-identical), with DPP/swizzle for low latency.
#pragma unroll
    for (int j = 0; j < 4; ++j) {
      p[j] += __shfl_xor(p[j], 32, 64);     // xor32 (ds_permute/permlane)
      p[j] = xadd_swz<0x401F>(p[j]);        // xor16 (ds_swizzle)
      p[j] = xadd_dpp<0x128>(p[j]);         // xor8  (DPP row_ror:8)
      p[j] = xadd_swz<0x101F>(p[j]);        // xor4  (ds_swizzle)
      p[j] = xadd_dpp<0x4E>(p[j]);          // xor2  (DPP quad_perm [2,3,0,1])
      p[j] = xadd_dpp<0xB1>(p[j]);          // xor1  (DPP quad_perm [1,0,3,2])
    }

    const float ic[4] = {icur4.x, icur4.y, icur4.z, icur4.w};
#pragma unroll
    for (int j = 0; j < 4; ++j)
      h[j] = fmaf(COEF, p[j] + ic[j] - h[j], h[j]);

    // ---- publish x(t+1) = relu(h), sign-encoded: this IS the barrier.
    if (t + 1 < TT) {
      const bool encN = (((t + 1) >> 1) & 1) != 0;
      if (l == 0) {
        i32x4 e;
        e.x = __builtin_bit_cast(int, fmaxf(h[0], 0.f));
        e.y = __builtin_bit_cast(int, fmaxf(h[1], 0.f));
        e.z = __builtin_bit_cast(int, fmaxf(h[2], 0.f));
        e.w = __builtin_bit_cast(int, fmaxf(h[3], 0.f));
        if (encN) e |= 0x80000000; else e &= 0x7fffffff;
        store_wt(xbuf + ((t + 1) & 1) * NN + rb, fc(e));
      }
    }
    // trace store: plain cached store (ack retires under the next poll)
    if (l == 0) {
      f32x4 hv; hv.x = h[0]; hv.y = h[1]; hv.z = h[2]; hv.w = h[3];
      *(f32x4*)(out_h + (size_t)t * NN + rb) = hv;
    }
  }
}

__global__ __launch_bounds__(256)
void readout(const float* __restrict__ h_all,
             const float* __restrict__ ro_w,
             const float* __restrict__ ro_b,
             float* __restrict__ y)
{
  __shared__ float red[4];
  const int t   = blockIdx.x;
  const int tid = threadIdx.x;
  const float* h = h_all + (size_t)t * NN;
  const int base = tid * 8;

  const float4 a0 = *(const float4*)(h + base);
  const float4 a1 = *(const float4*)(h + base + 4);
  const float4 w0 = *(const float4*)(ro_w + base);
  const float4 w1 = *(const float4*)(ro_w + base + 4);

  float s = a0.x * w0.x + a0.y * w0.y + a0.z * w0.z + a0.w * w0.w
          + a1.x * w1.x + a1.y * w1.y + a1.z * w1.z + a1.w * w1.w;
#pragma unroll
  for (int m = 32; m >= 1; m >>= 1) s += __shfl_xor(s, m, 64);

  if ((tid & 63) == 0) red[tid >> 6] = s;
  __syncthreads();
  if (tid == 0) y[t] = red[0] + red[1] + red[2] + red[3] + ro_b[0];
}

extern "C" void kernel_launch(void* const* d_in, const int* in_sizes, int n_in,
                              void* d_out, int out_size, void* d_ws, size_t ws_size,
                              hipStream_t stream)
{
  const float* I_t  = (const float*)d_in[0];
  const float* h0   = (const float*)d_in[1];
  const float* W    = (const float*)d_in[2];
  const float* u    = (const float*)d_in[3];
  const float* v    = (const float*)d_in[4];
  const float* ro_w = (const float*)d_in[5];
  const float* ro_b = (const float*)d_in[6];

  float* y    = (float*)d_out;             // [TT]
  float* outh = (float*)d_out + TT;        // [TT][NN]

  float* xbuf = (float*)d_ws;              // 2*NN floats

  init_xbufs<<<NN / TPB, TPB, 0, stream>>>(xbuf);
  rnn_persist<<<NBLK, TPB, 0, stream>>>(I_t, h0, W, u, v, outh, xbuf);
  readout<<<TT, 256, 0, stream>>>(outh, ro_w, ro_b, y);
}